// Round 2
// baseline (1295.266 us; speedup 1.0000x reference)
//
#include <hip/hip_runtime.h>
#include <math.h>

#define NPTS 131072
#define KCOMP 256
#define DIM 32

// Packed triangular A in bf16: row d covers f = 8*(d/8) .. 31 (front-padded to
// 8-element / 16-byte alignment); entries below the diagonal are 0, diagonal is
// A_dd, above-diagonal are 2*A_df. Group g = d/8 has row length 32-8g.
// Group starts (in bf16 elements): 0, 256, 448, 576; total 640 per k.
#define UPACK_LEN 640
#define WS_NEED ((size_t)KCOMP * UPACK_LEN * 2 + (size_t)KCOMP * 4)

__device__ __forceinline__ float bf_lo(unsigned r) { return __uint_as_float(r << 16); }
__device__ __forceinline__ float bf_hi(unsigned r) { return __uint_as_float(r & 0xffff0000u); }

__device__ __forceinline__ unsigned short f2bf(float v) {
    unsigned u = __float_as_uint(v);
    u += 0x7fffu + ((u >> 16) & 1u);   // round-to-nearest-even
    return (unsigned short)(u >> 16);
}

// In-place Cholesky (lower triangle) of SPD As; all 256 threads participate.
__device__ void chol32(float (*As)[DIM + 1], int tid) {
    for (int j = 0; j < DIM; ++j) {
        if (tid == 0) As[j][j] = sqrtf(As[j][j]);
        __syncthreads();
        if (tid > j && tid < DIM) As[tid][j] /= As[j][j];
        __syncthreads();
        for (int idx = tid; idx < DIM * DIM; idx += 256) {
            const int r = idx >> 5, c = idx & 31;
            if (r > j && c > j && c <= r)
                As[r][c] = fmaf(-As[r][j], As[c][j], As[r][c]);
        }
        __syncthreads();
    }
}

// ---------------------------------------------------------------------------
// Fast-path precompute: Ubf (packed bf16 A), kc[k] = log|w_k| - log(sum|w|)
//                       + 0.5*logdet(A_k)
// ---------------------------------------------------------------------------
__global__ __launch_bounds__(256) void gmm_pre(
    const float* __restrict__ S,        // covs_inv_sqrt [K, D, D]
    const float* __restrict__ weights,  // [K]
    unsigned short* __restrict__ Ubf,   // [K, UPACK_LEN]
    float* __restrict__ kc)             // [K]
{
    __shared__ float Sl[DIM][DIM + 1];
    __shared__ float As[DIM][DIM + 1];
    __shared__ float red[256];

    const int k = blockIdx.x;
    const int tid = threadIdx.x;

    for (int idx = tid; idx < DIM * DIM; idx += 256)
        Sl[idx >> 5][idx & 31] = S[(size_t)k * DIM * DIM + idx];
    __syncthreads();

    // A = S S^T
    for (int idx = tid; idx < DIM * DIM; idx += 256) {
        const int d = idx >> 5, f = idx & 31;
        float a = 0.f;
#pragma unroll
        for (int e = 0; e < DIM; ++e) a = fmaf(Sl[d][e], Sl[f][e], a);
        As[d][f] = a;
    }
    __syncthreads();

    // pack upper triangle (reads As upper+diag only)
    for (int p = tid; p < UPACK_LEN; p += 256) {
        int g, base;
        if (p < 256)      { g = 0; base = 0;   }
        else if (p < 448) { g = 1; base = 256; }
        else if (p < 576) { g = 2; base = 448; }
        else              { g = 3; base = 576; }
        const int L = 32 - 8 * g;
        const int dd = (p - base) / L, j = (p - base) % L;
        const int d = 8 * g + dd, f = 8 * g + j;
        const float v = (f < d) ? 0.f : ((f == d) ? As[d][f] : 2.f * As[d][f]);
        Ubf[(size_t)k * UPACK_LEN + p] = f2bf(v);
    }

    // sum |weights| (K == 256 == blockDim); barrier also fences As reads above
    red[tid] = fabsf(weights[tid]);
    __syncthreads();
    for (int off = 128; off > 0; off >>= 1) {
        if (tid < off) red[tid] += red[tid + off];
        __syncthreads();
    }
    const float wsum = red[0];

    chol32(As, tid);   // modifies diag+lower only, after all barriers above

    if (tid == 0) {
        float ld = 0.f;
        for (int j = 0; j < DIM; ++j) ld += logf(As[j][j]);  // = 0.5*logdet(A)
        kc[k] = logf(fabsf(weights[k])) - logf(wsum + 1e-30f) + ld;
    }
}

// ---------------------------------------------------------------------------
// Fast-path main: 1 thread/point; 8-k chunks of Ubf/centers/kc staged in LDS;
// q = z^T A z via packed bf16 rows (unpack = 1 VALU op/value); online LSE.
// ---------------------------------------------------------------------------
__global__ __launch_bounds__(256) void gmm_main(
    const float* __restrict__ points,
    const unsigned short* __restrict__ Ubf,
    const float* __restrict__ centers,
    const float* __restrict__ kc,
    const float* __restrict__ thr,
    float* __restrict__ out)
{
    __shared__ alignas(16) unsigned short sU[8 * UPACK_LEN];
    __shared__ alignas(16) float sC[8 * DIM];
    __shared__ float sKc[8];

    const int tid = threadIdx.x;
    const int i = blockIdx.x * 256 + tid;

    float x[DIM];
    {
        const float4* px = reinterpret_cast<const float4*>(points + (size_t)i * DIM);
#pragma unroll
        for (int j = 0; j < DIM / 4; ++j) {
            float4 v = px[j];
            x[4 * j + 0] = v.x; x[4 * j + 1] = v.y;
            x[4 * j + 2] = v.z; x[4 * j + 3] = v.w;
        }
    }

    float Mx = -INFINITY, s = 0.f;

#pragma unroll 1
    for (int ch = 0; ch < KCOMP / 8; ++ch) {
        __syncthreads();
        {
            const uint4* g4 = reinterpret_cast<const uint4*>(Ubf + (size_t)ch * 8 * UPACK_LEN);
            uint4* s4 = reinterpret_cast<uint4*>(sU);
            for (int j = tid; j < 8 * UPACK_LEN / 8; j += 256) s4[j] = g4[j];
        }
        if (tid < 64)
            reinterpret_cast<float4*>(sC)[tid] =
                reinterpret_cast<const float4*>(centers + (size_t)ch * 8 * DIM)[tid];
        if (tid < 8) sKc[tid] = kc[ch * 8 + tid];
        __syncthreads();

#pragma unroll 1
        for (int kk = 0; kk < 8; ++kk) {
            float z[DIM];
#pragma unroll
            for (int d = 0; d < DIM; ++d) z[d] = x[d] - sC[kk * DIM + d];

            const uint4* Uk = reinterpret_cast<const uint4*>(sU + kk * UPACK_LEN);
            float q = 0.f;
            int p4 = 0;
#pragma unroll
            for (int g = 0; g < 4; ++g) {
#pragma unroll
                for (int dd = 0; dd < 8; ++dd) {
                    const int d = 8 * g + dd;
                    float t = 0.f;
#pragma unroll
                    for (int v = 0; v < 4 - g; ++v) {
                        const uint4 u = Uk[p4++];
                        const int f0 = 8 * g + 8 * v;
                        t = fmaf(bf_lo(u.x), z[f0 + 0], t);
                        t = fmaf(bf_hi(u.x), z[f0 + 1], t);
                        t = fmaf(bf_lo(u.y), z[f0 + 2], t);
                        t = fmaf(bf_hi(u.y), z[f0 + 3], t);
                        t = fmaf(bf_lo(u.z), z[f0 + 4], t);
                        t = fmaf(bf_hi(u.z), z[f0 + 5], t);
                        t = fmaf(bf_lo(u.w), z[f0 + 6], t);
                        t = fmaf(bf_hi(u.w), z[f0 + 7], t);
                    }
                    q = fmaf(z[d], t, q);
                }
            }
            const float gk = fmaf(-0.5f, q, sKc[kk]);
            const float Mn = fmaxf(Mx, gk);
            s = fmaf(s, __expf(Mx - Mn), __expf(gk - Mn));
            Mx = Mn;
        }
    }
    out[i] = Mx + __logf(s) - thr[0];
}

// ---------------------------------------------------------------------------
// Workspace-free fallback (insurance if ws_size < WS_NEED). Each block
// recomputes kc[0..K) via per-k Cholesky, then streams S_k through LDS with
// q = ||S^T z||^2. Slow (~2 ms) but correct and touches no scratch memory.
// ---------------------------------------------------------------------------
__global__ __launch_bounds__(256) void gmm_fallback(
    const float* __restrict__ points,
    const float* __restrict__ centers,
    const float* __restrict__ S,
    const float* __restrict__ weights,
    const float* __restrict__ thr,
    float* __restrict__ out)
{
    __shared__ float As[DIM][DIM + 1];
    __shared__ float kcL[KCOMP];
    __shared__ float red[256];
    __shared__ alignas(16) float Sf[DIM * DIM];
    __shared__ float cl[DIM];

    const int tid = threadIdx.x;

    red[tid] = fabsf(weights[tid]);
    __syncthreads();
    for (int off = 128; off > 0; off >>= 1) {
        if (tid < off) red[tid] += red[tid + off];
        __syncthreads();
    }
    const float wsum = red[0];

    // phase 1: kc for all k (A built straight from global S; L1-resident)
    for (int k = 0; k < KCOMP; ++k) {
        __syncthreads();
        const float* Sk = S + (size_t)k * DIM * DIM;
        for (int idx = tid; idx < DIM * DIM; idx += 256) {
            const int d = idx >> 5, f = idx & 31;
            float a = 0.f;
#pragma unroll
            for (int e = 0; e < DIM; ++e) a = fmaf(Sk[d * DIM + e], Sk[f * DIM + e], a);
            As[d][f] = a;
        }
        __syncthreads();
        chol32(As, tid);
        if (tid == 0) {
            float ld = 0.f;
            for (int j = 0; j < DIM; ++j) ld += logf(As[j][j]);
            kcL[k] = logf(fabsf(weights[k])) - logf(wsum + 1e-30f) + ld;
        }
    }
    __syncthreads();

    // phase 2: points
    const int i = blockIdx.x * 256 + tid;
    float x[DIM];
    {
        const float4* px = reinterpret_cast<const float4*>(points + (size_t)i * DIM);
#pragma unroll
        for (int j = 0; j < DIM / 4; ++j) {
            float4 v = px[j];
            x[4 * j + 0] = v.x; x[4 * j + 1] = v.y;
            x[4 * j + 2] = v.z; x[4 * j + 3] = v.w;
        }
    }
    float Mx = -INFINITY, s = 0.f;
#pragma unroll 1
    for (int k = 0; k < KCOMP; ++k) {
        __syncthreads();
        for (int idx = tid; idx < DIM * DIM; idx += 256)
            Sf[idx] = S[(size_t)k * DIM * DIM + idx];
        if (tid < DIM) cl[tid] = centers[k * DIM + tid];
        __syncthreads();

        float z[DIM];
#pragma unroll
        for (int d = 0; d < DIM; ++d) z[d] = x[d] - cl[d];
        float y[DIM];
#pragma unroll
        for (int e = 0; e < DIM; ++e) y[e] = 0.f;
#pragma unroll
        for (int d = 0; d < DIM; ++d) {
            const float4* row = reinterpret_cast<const float4*>(Sf + d * DIM);
            const float zd = z[d];
#pragma unroll
            for (int v = 0; v < DIM / 4; ++v) {
                const float4 u = row[v];
                y[4 * v + 0] = fmaf(u.x, zd, y[4 * v + 0]);
                y[4 * v + 1] = fmaf(u.y, zd, y[4 * v + 1]);
                y[4 * v + 2] = fmaf(u.z, zd, y[4 * v + 2]);
                y[4 * v + 3] = fmaf(u.w, zd, y[4 * v + 3]);
            }
        }
        float q = 0.f;
#pragma unroll
        for (int e = 0; e < DIM; ++e) q = fmaf(y[e], y[e], q);

        const float gk = fmaf(-0.5f, q, kcL[k]);
        const float Mn = fmaxf(Mx, gk);
        s = fmaf(s, __expf(Mx - Mn), __expf(gk - Mn));
        Mx = Mn;
    }
    out[i] = Mx + __logf(s) - thr[0];
}

extern "C" void kernel_launch(void* const* d_in, const int* in_sizes, int n_in,
                              void* d_out, int out_size, void* d_ws, size_t ws_size,
                              hipStream_t stream) {
    const float* points  = (const float*)d_in[0];   // [N, D]
    const float* centers = (const float*)d_in[1];   // [K, D]
    const float* covs    = (const float*)d_in[2];   // [K, D, D]
    const float* weights = (const float*)d_in[3];   // [K]
    const float* thr     = (const float*)d_in[4];   // [1]
    float* out = (float*)d_out;

    // ws_size is identical on every call, so this branch is the same work
    // every call (round-1 failure signature == OOB scratch writes corrupting
    // neighboring allocations; stay strictly within ws_size).
    if (ws_size >= WS_NEED) {
        unsigned short* Ubf = (unsigned short*)d_ws;
        float* kcb = (float*)((char*)d_ws + (size_t)KCOMP * UPACK_LEN * 2);
        gmm_pre<<<KCOMP, 256, 0, stream>>>(covs, weights, Ubf, kcb);
        gmm_main<<<NPTS / 256, 256, 0, stream>>>(points, Ubf, centers, kcb, thr, out);
    } else {
        gmm_fallback<<<NPTS / 256, 256, 0, stream>>>(points, centers, covs, weights, thr, out);
    }
}

// Round 3
// 161.305 us; speedup vs baseline: 8.0299x; 8.0299x over previous
//
#include <hip/hip_runtime.h>
#include <math.h>

#define NPTS 131072
#define KCOMP 256
#define DIM 32
#define KF 608                    // 576 quad features (4-aligned rows) + 32 m
#define PSIF_BYTES 311296         // 19456 granules * 16 B
#define WS_NEED (PSIF_BYTES + KCOMP * 4)

typedef __attribute__((ext_vector_type(8))) short short8;
typedef __attribute__((ext_vector_type(16))) float f32x16;

__device__ __forceinline__ unsigned short f2bf(float v) {
    unsigned u = __float_as_uint(v);
    u += 0x7fffu + ((u >> 16) & 1u);   // RNE
    return (unsigned short)(u >> 16);
}

// ---- compile-time feature decode: quad-packed triangular, 4-aligned rows ----
// row d covers f in [d&~3, 31], padded length L4 = ceil((32-d)/4)*4; sum = 576.
constexpr int L4c(int d) { return ((32 - d + 3) / 4) * 4; }
constexpr int PfxC(int d) { int s = 0; for (int i = 0; i < d; ++i) s += L4c(i); return s; }
constexpr int rowOfC(int p) { int d = 0; while (d < 31 && PfxC(d + 1) <= p) ++d; return d; }
constexpr int dOfC(int p) { return (p >= 576) ? -1 : rowOfC(p); }
constexpr int f0OfC(int p) {
    return (p >= 576) ? (p - 576) : ((rowOfC(p) & ~3) + (p - PfxC(rowOfC(p))));
}

// ---------------------------------------------------------------------------
// Precompute: Psi column k scattered into frag-ordered PsiF (bf16), kc2 fp32.
// Psi[p<576] = -0.5*A_dd (diag) / -A_df (off-diag) / 0 (pad);  Psi[576+i]=m_i.
// kc2 = log|w| - log(sum|w|) + 0.5*logdet(A) - 0.5*c'Ac.
// ---------------------------------------------------------------------------
__global__ __launch_bounds__(256) void gmm_pre(
    const float* __restrict__ S,
    const float* __restrict__ centers,
    const float* __restrict__ weights,
    unsigned short* __restrict__ PsiF,
    float* __restrict__ kc2)
{
    __shared__ float Sl[DIM][DIM + 1];
    __shared__ float As[DIM][DIM + 1];
    __shared__ float cl[DIM], ml[DIM];
    __shared__ float red[256];

    const int k = blockIdx.x, tid = threadIdx.x;

    for (int idx = tid; idx < DIM * DIM; idx += 256)
        Sl[idx >> 5][idx & 31] = S[(size_t)k * DIM * DIM + idx];
    if (tid < DIM) cl[tid] = centers[k * DIM + tid];
    __syncthreads();

    // A = S S^T
    for (int idx = tid; idx < DIM * DIM; idx += 256) {
        const int d = idx >> 5, f = idx & 31;
        float a = 0.f;
#pragma unroll
        for (int e = 0; e < DIM; ++e) a = fmaf(Sl[d][e], Sl[f][e], a);
        As[d][f] = a;
    }
    __syncthreads();

    if (tid < DIM) {
        float mv = 0.f;
#pragma unroll
        for (int f = 0; f < DIM; ++f) mv = fmaf(As[tid][f], cl[f], mv);
        ml[tid] = mv;
    }
    __syncthreads();

    // scatter Psi column k into frag positions
    for (int p = tid; p < KF; p += 256) {
        float val;
        if (p < 576) {
            int d = 0, pr = 0;
            while (true) {
                const int len = ((32 - d + 3) >> 2) << 2;
                if (pr + len > p) break;
                pr += len; ++d;
            }
            const int f = (d & ~3) + (p - pr);
            val = (f < d) ? 0.f : ((f == d) ? -0.5f * As[d][d] : -As[d][f]);
        } else {
            val = ml[p - 576];
        }
        const int c = p >> 6, kk = p & 63;
        const int s = kk >> 4, qq = (kk >> 3) & 1, j = kk & 7;
        const int ct = k >> 5, ll = qq * 32 + (k & 31);
        const int g = c * 2048 + (s * 8 + ct) * 64 + ll;
        PsiF[(size_t)g * 8 + j] = f2bf(val);
    }

    red[tid] = fabsf(weights[tid]);          // K == 256 == blockDim
    __syncthreads();                          // also fences As reads above
    for (int off = 128; off > 0; off >>= 1) {
        if (tid < off) red[tid] += red[tid + off];
        __syncthreads();
    }
    const float wsum = red[0];

    // in-place Cholesky (destroys diag+lower of As; all consumers are done)
    for (int j = 0; j < DIM; ++j) {
        if (tid == 0) As[j][j] = sqrtf(As[j][j]);
        __syncthreads();
        if (tid > j && tid < DIM) As[tid][j] /= As[j][j];
        __syncthreads();
        for (int idx = tid; idx < DIM * DIM; idx += 256) {
            const int r = idx >> 5, cc = idx & 31;
            if (r > j && cc > j && cc <= r)
                As[r][cc] = fmaf(-As[r][j], As[cc][j], As[r][cc]);
        }
        __syncthreads();
    }

    if (tid == 0) {
        float ld = 0.f;
        for (int j = 0; j < DIM; ++j) ld += logf(As[j][j]);  // 0.5*logdet(A)
        float cac = 0.f;
        for (int d2 = 0; d2 < DIM; ++d2) cac = fmaf(ml[d2], cl[d2], cac);
        kc2[k] = logf(fabsf(weights[k])) - logf(wsum + 1e-30f) + ld - 0.5f * cac;
    }
}

// ---------------------------------------------------------------------------
// Main MFMA kernel
// ---------------------------------------------------------------------------
template<int P>
__device__ __forceinline__ void genQuad(const float (&x)[DIM], float* v) {
    constexpr int d = dOfC(P);
    constexpr int f0 = f0OfC(P);
#pragma unroll
    for (int j = 0; j < 4; ++j)
        v[j] = (d < 0) ? x[f0 + j] : (x[d] * x[f0 + j]);
}

template<int C, int SS>
__device__ __forceinline__ void genSite(const float (&x)[DIM], uint4* sA4,
                                        int rbg, int r32) {
    float v[8];
    genQuad<C * 64 + SS * 8>(x, v);
    genQuad<C * 64 + SS * 8 + 4>(x, v + 4);
    uint4 u;
    u.x = (unsigned)f2bf(v[0]) | ((unsigned)f2bf(v[1]) << 16);
    u.y = (unsigned)f2bf(v[2]) | ((unsigned)f2bf(v[3]) << 16);
    u.z = (unsigned)f2bf(v[4]) | ((unsigned)f2bf(v[5]) << 16);
    u.w = (unsigned)f2bf(v[6]) | ((unsigned)f2bf(v[7]) << 16);
    sA4[(SS >> 1) * 256 + rbg * 64 + (SS & 1) * 32 + r32] = u;
}

template<int C>
__device__ __forceinline__ void doChunk(const float (&x)[DIM],
    uint4* sA4, uint4* sB4, const uint4* __restrict__ PsiF4,
    f32x16 (&acc0)[4], f32x16 (&acc1)[4],
    int t, int l, int q, int rbg, int r32, int r0, int c0)
{
    constexpr int NS = (C < 9) ? 4 : 2;   // K16-steps in this chunk
    if (q == 0) {
        genSite<C, 0>(x, sA4, rbg, r32);
        genSite<C, 2>(x, sA4, rbg, r32);
        if constexpr (NS == 4) { genSite<C, 4>(x, sA4, rbg, r32); genSite<C, 6>(x, sA4, rbg, r32); }
    } else {
        genSite<C, 1>(x, sA4, rbg, r32);
        genSite<C, 3>(x, sA4, rbg, r32);
        if constexpr (NS == 4) { genSite<C, 5>(x, sA4, rbg, r32); genSite<C, 7>(x, sA4, rbg, r32); }
    }
    const uint4* src = PsiF4 + C * 2048;   // frag-ordered, contiguous copy
#pragma unroll
    for (int m = 0; m < NS * 2; ++m)
        sB4[m * 256 + t] = src[m * 256 + t];
    __syncthreads();
#pragma unroll
    for (int s = 0; s < NS; ++s) {
        short8 a0 = __builtin_bit_cast(short8, sA4[(s * 4 + r0) * 64 + l]);
        short8 a1 = __builtin_bit_cast(short8, sA4[(s * 4 + r0 + 1) * 64 + l]);
#pragma unroll
        for (int j = 0; j < 4; ++j) {
            short8 b = __builtin_bit_cast(short8, sB4[(s * 8 + c0 + j) * 64 + l]);
            acc0[j] = __builtin_amdgcn_mfma_f32_32x32x16_bf16(a0, b, acc0[j], 0, 0, 0);
            acc1[j] = __builtin_amdgcn_mfma_f32_32x32x16_bf16(a1, b, acc1[j], 0, 0, 0);
        }
    }
    __syncthreads();
}

__device__ __forceinline__ void epiHalf(const f32x16 (&acc)[4], const float (&kcv)[4],
    int rblock, int l, int whalf, float (*sM)[2], float (*sS)[2])
{
#pragma unroll
    for (int rg = 0; rg < 16; ++rg) {
        float vals[4], m = -INFINITY;
#pragma unroll
        for (int j = 0; j < 4; ++j) { vals[j] = acc[j][rg] + kcv[j]; m = fmaxf(m, vals[j]); }
#pragma unroll
        for (int mask = 1; mask < 32; mask <<= 1) m = fmaxf(m, __shfl_xor(m, mask, 64));
        float sv = 0.f;
#pragma unroll
        for (int j = 0; j < 4; ++j) sv += __expf(vals[j] - m);
#pragma unroll
        for (int mask = 1; mask < 32; mask <<= 1) sv += __shfl_xor(sv, mask, 64);
        if ((l & 31) == 0) {
            const int R = rblock * 32 + (rg & 3) + 8 * (rg >> 2) + 4 * (l >> 5);
            sM[R][whalf] = m; sS[R][whalf] = sv;
        }
    }
}

__global__ __launch_bounds__(256, 2) void gmm_mfma(
    const float* __restrict__ points,
    const unsigned short* __restrict__ PsiF,
    const float* __restrict__ kc2,
    const float* __restrict__ thr,
    float* __restrict__ out)
{
    __shared__ uint4 sA4[1024];          // 16 KB: 128 rows x 64 k, frag order
    __shared__ uint4 sB4[2048];          // 32 KB: 64 k x 256 cols, frag order
    __shared__ float sM[128][2], sS[128][2];

    const int t = threadIdx.x;
    const int w = t >> 6, l = t & 63;
    const int row = t & 127, q = t >> 7;          // gen role: 2 threads/row
    const int rbg = row >> 5, r32 = row & 31;
    const int r0 = (w >> 1) * 2, c0 = (w & 1) * 4; // mfma wave tile: 64r x 128c

    float x[DIM];
    const float4* px = (const float4*)(points + ((size_t)blockIdx.x * 128 + row) * DIM);
#pragma unroll
    for (int j2 = 0; j2 < 8; ++j2) {
        float4 v = px[j2];
        x[4 * j2 + 0] = v.x; x[4 * j2 + 1] = v.y;
        x[4 * j2 + 2] = v.z; x[4 * j2 + 3] = v.w;
    }

    f32x16 acc0[4], acc1[4];
#pragma unroll
    for (int j = 0; j < 4; ++j)
#pragma unroll
        for (int r = 0; r < 16; ++r) { acc0[j][r] = 0.f; acc1[j][r] = 0.f; }

    const uint4* PsiF4 = (const uint4*)PsiF;
    doChunk<0>(x, sA4, sB4, PsiF4, acc0, acc1, t, l, q, rbg, r32, r0, c0);
    doChunk<1>(x, sA4, sB4, PsiF4, acc0, acc1, t, l, q, rbg, r32, r0, c0);
    doChunk<2>(x, sA4, sB4, PsiF4, acc0, acc1, t, l, q, rbg, r32, r0, c0);
    doChunk<3>(x, sA4, sB4, PsiF4, acc0, acc1, t, l, q, rbg, r32, r0, c0);
    doChunk<4>(x, sA4, sB4, PsiF4, acc0, acc1, t, l, q, rbg, r32, r0, c0);
    doChunk<5>(x, sA4, sB4, PsiF4, acc0, acc1, t, l, q, rbg, r32, r0, c0);
    doChunk<6>(x, sA4, sB4, PsiF4, acc0, acc1, t, l, q, rbg, r32, r0, c0);
    doChunk<7>(x, sA4, sB4, PsiF4, acc0, acc1, t, l, q, rbg, r32, r0, c0);
    doChunk<8>(x, sA4, sB4, PsiF4, acc0, acc1, t, l, q, rbg, r32, r0, c0);
    doChunk<9>(x, sA4, sB4, PsiF4, acc0, acc1, t, l, q, rbg, r32, r0, c0);

    // epilogue: add kc2, row-wise LSE over 256 cols (two 128-col halves)
    float kcv[4];
#pragma unroll
    for (int j = 0; j < 4; ++j) kcv[j] = kc2[(c0 + j) * 32 + (l & 31)];

    epiHalf(acc0, kcv, r0,     l, w & 1, sM, sS);
    epiHalf(acc1, kcv, r0 + 1, l, w & 1, sM, sS);
    __syncthreads();

    if (t < 128) {
        const float m0 = sM[t][0], m1 = sM[t][1];
        const float M = fmaxf(m0, m1);
        const float Sv = sS[t][0] * __expf(m0 - M) + sS[t][1] * __expf(m1 - M);
        out[(size_t)blockIdx.x * 128 + t] = M + __logf(Sv) - thr[0];
    }
}

extern "C" void kernel_launch(void* const* d_in, const int* in_sizes, int n_in,
                              void* d_out, int out_size, void* d_ws, size_t ws_size,
                              hipStream_t stream) {
    const float* points  = (const float*)d_in[0];
    const float* centers = (const float*)d_in[1];
    const float* covs    = (const float*)d_in[2];
    const float* weights = (const float*)d_in[3];
    const float* thr     = (const float*)d_in[4];
    float* out = (float*)d_out;

    // 312,320 B needed; round 2 proved ws_size >= 328,704, so this always fits.
    unsigned short* PsiF = (unsigned short*)d_ws;
    float* kc2 = (float*)((char*)d_ws + PSIF_BYTES);

    gmm_pre<<<KCOMP, 256, 0, stream>>>(covs, centers, weights, PsiF, kc2);
    gmm_mfma<<<NPTS / 128, 256, 0, stream>>>(points, PsiF, kc2, thr, out);
}